// Round 9
// baseline (531.177 us; speedup 1.0000x reference)
//
#include <hip/hip_runtime.h>
#include <cmath>

#define NN 50000
#define KK 15
#define DD 128
#define HH 64
#define NKE (NN * KK)
// ws layout: [ xT : DD*NN ][ XA : NN*HH ][ XB : NN*HH ][ XC : NN*HH ]
#define TOFF ((size_t)DD * NN)
#define WS_NEED ((TOFF + 3 * (size_t)NN * HH) * 4)

// ---------------------------------------------------------------------------
// kT: transpose x (NN x DD) -> xT (DD x NN) via padded LDS tile.
// ---------------------------------------------------------------------------
__global__ __launch_bounds__(256) void kT(const float* __restrict__ x,
                                          float* __restrict__ xT) {
    __shared__ float s[64][DD + 1];
    int t = threadIdx.x;
    int r0 = blockIdx.x * 64;
#pragma unroll
    for (int i = 0; i < 8; ++i) {
        int idx = i * 256 + t;
        int rr = idx >> 5, cc = idx & 31;
        if (r0 + rr < NN) {
            float4 v = *(const float4*)(x + (size_t)(r0 + rr) * DD + cc * 4);
            s[rr][cc * 4 + 0] = v.x; s[rr][cc * 4 + 1] = v.y;
            s[rr][cc * 4 + 2] = v.z; s[rr][cc * 4 + 3] = v.w;
        }
    }
    __syncthreads();
    int lane = t & 63, wq = t >> 6;
    int n = r0 + lane;
    if (n >= NN) return;
#pragma unroll
    for (int i = 0; i < 32; ++i) {
        int k = i * 4 + wq;
        xT[(size_t)k * NN + n] = s[lane][k];
    }
}

// ---------------------------------------------------------------------------
// kP4: per-node GEMM (kP2 operand paths) + IN-BLOCK K-SPLIT for 2x waves.
// Block 256 = 128 nodes x 2 k-halves; grid (ceil(NN/128), 3 segs).
// Each thread: acc[64] over its 64 k's — coalesced xT dword loads (lane=n),
// wave-uniform s_load W rows (16 KB stream per wave = kE's proven footprint).
// k-half-1 dumps acc to LDS [j][n] (conflict-free), k-half-0 adds + stores
// (low-k chain + high-k chain: deterministic).  4692 waves vs kP2's 2346.
// ---------------------------------------------------------------------------
__global__ __launch_bounds__(256, 4) void kP4(const float* __restrict__ xT,
                                              const float* __restrict__ ew1,
                                              const float* __restrict__ dw1,
                                              float* __restrict__ xabc) {
    __shared__ float comb[HH * 128];          // [j][nloc], 32 KB
    int seg = blockIdx.y;
    const float* W = (seg == 0) ? ew1 : (seg == 1) ? (ew1 + DD * HH) : dw1;
    int t = threadIdx.x;
    int nloc = t & 127;
    int kh = t >> 7;                          // wave-uniform (waves 0,1 / 2,3)
    int n = blockIdx.x * 128 + nloc;
    bool active = (n < NN);

    float acc[HH];
#pragma unroll
    for (int j = 0; j < HH; ++j) acc[j] = 0.f;

    if (active) {
#pragma unroll 1
        for (int k4 = kh * 16; k4 < kh * 16 + 16; ++k4) {
            float x0 = xT[(size_t)(k4 * 4 + 0) * NN + n];   // coalesced
            float x1 = xT[(size_t)(k4 * 4 + 1) * NN + n];
            float x2 = xT[(size_t)(k4 * 4 + 2) * NN + n];
            float x3 = xT[(size_t)(k4 * 4 + 3) * NN + n];
            float xv[4] = {x0, x1, x2, x3};
#pragma unroll
            for (int m = 0; m < 4; ++m) {
                const float* wr = W + (k4 * 4 + m) * HH;     // uniform -> s_load
#pragma unroll
                for (int j4 = 0; j4 < 16; ++j4) {
                    float4 w = *(const float4*)(wr + j4 * 4);
                    acc[j4 * 4 + 0] = fmaf(xv[m], w.x, acc[j4 * 4 + 0]);
                    acc[j4 * 4 + 1] = fmaf(xv[m], w.y, acc[j4 * 4 + 1]);
                    acc[j4 * 4 + 2] = fmaf(xv[m], w.z, acc[j4 * 4 + 2]);
                    acc[j4 * 4 + 3] = fmaf(xv[m], w.w, acc[j4 * 4 + 3]);
                }
            }
        }
    }
    // combine halves through LDS [j][nloc]: per-j lanes are consecutive words
    if (kh == 1) {
#pragma unroll
        for (int j = 0; j < HH; ++j) comb[j * 128 + nloc] = acc[j];
    }
    __syncthreads();
    if (kh == 0 && active) {
#pragma unroll
        for (int j = 0; j < HH; ++j) acc[j] += comb[j * 128 + nloc];
        float* orow = xabc + (size_t)seg * NN * HH + (size_t)n * HH;
#pragma unroll
        for (int j4 = 0; j4 < 16; ++j4) {
            float4 v;
            v.x = acc[j4 * 4 + 0]; v.y = acc[j4 * 4 + 1];
            v.z = acc[j4 * 4 + 2]; v.w = acc[j4 * 4 + 3];
            *(float4*)(orow + j4 * 4) = v;
        }
    }
}

// ---------------------------------------------------------------------------
// kEF: fused edge-MLP + node-MLP + sort.  Block 960 = 64 nodes x 15 edges.
// Phase 1 = kE verbatim (thread-per-edge, acc[64] AGPR, s_load ew2, XB
// prefetch depth 2), energy -> global AND LDS.  One barrier.  Phase 2 =
// wave 0 thread-per-node: degree MLP (acc[64], s_load dw2) + register sort
// + hard gate + normalize.  Phase-2 latency hides under other blocks'
// phase-1 waves; saves two kernel launches.
// ---------------------------------------------------------------------------
__global__ __launch_bounds__(960, 4) void kEF(const int* __restrict__ srcIdx,
                                              const float* __restrict__ dist,
                                              const float* __restrict__ xabc,
                                              const float* __restrict__ ew1,
                                              const float* __restrict__ eb1,
                                              const float* __restrict__ ew2,
                                              const float* __restrict__ eb2,
                                              const float* __restrict__ ew3,
                                              const float* __restrict__ eb3,
                                              const float* __restrict__ dw1,
                                              const float* __restrict__ db1,
                                              const float* __restrict__ dw2,
                                              const float* __restrict__ db2,
                                              const float* __restrict__ dw3,
                                              const float* __restrict__ db3,
                                              float* __restrict__ out) {
    __shared__ float ebuf[960];
    int e = blockIdx.x * 960 + threadIdx.x;
    float* energy_out = out + 2 * (size_t)NKE;

    if (e < NKE) {
        int s = srcIdx[e];
        int d = e / KK;
        float dd = dist[e];
        const float* A = xabc + (size_t)d * HH;
        const float* B = xabc + (size_t)NN * HH + (size_t)s * HH;
        const float* w1l = ew1 + 2 * DD * HH;

        float acc[HH];
#pragma unroll
        for (int j = 0; j < HH; ++j) acc[j] = 0.f;

        float4 a4 = *(const float4*)A;
        float4 bp0 = *(const float4*)B;
        float4 bp1 = *(const float4*)(B + 4);
#pragma unroll 1
        for (int i4 = 0; i4 < HH / 4; ++i4) {
            float4 a = a4, b = bp0;
            int n1 = (i4 + 1 < 16) ? (i4 + 1) : 15;
            int n2 = (i4 + 2 < 16) ? (i4 + 2) : 15;
            a4 = *(const float4*)(A + n1 * 4);
            bp0 = bp1;
            bp1 = *(const float4*)(B + n2 * 4);
            float h[4];
            h[0] = fmaxf(a.x + b.x + dd * w1l[i4 * 4 + 0] + eb1[i4 * 4 + 0], 0.f);
            h[1] = fmaxf(a.y + b.y + dd * w1l[i4 * 4 + 1] + eb1[i4 * 4 + 1], 0.f);
            h[2] = fmaxf(a.z + b.z + dd * w1l[i4 * 4 + 2] + eb1[i4 * 4 + 2], 0.f);
            h[3] = fmaxf(a.w + b.w + dd * w1l[i4 * 4 + 3] + eb1[i4 * 4 + 3], 0.f);
#pragma unroll
            for (int k = 0; k < 4; ++k) {
                const float* wr = ew2 + (i4 * 4 + k) * HH;
#pragma unroll
                for (int j4 = 0; j4 < 16; ++j4) {
                    float4 w = *(const float4*)(wr + j4 * 4);
                    acc[j4 * 4 + 0] = fmaf(h[k], w.x, acc[j4 * 4 + 0]);
                    acc[j4 * 4 + 1] = fmaf(h[k], w.y, acc[j4 * 4 + 1]);
                    acc[j4 * 4 + 2] = fmaf(h[k], w.z, acc[j4 * 4 + 2]);
                    acc[j4 * 4 + 3] = fmaf(h[k], w.w, acc[j4 * 4 + 3]);
                }
            }
        }
        float lg = eb3[0];
#pragma unroll
        for (int j = 0; j < HH; ++j)
            lg = fmaf(fmaxf(acc[j] + eb2[j], 0.f), ew3[j], lg);
        float en = 1.f / (1.f + expf(-2.f * lg));
        energy_out[e] = en;
        ebuf[threadIdx.x] = en;
    }
    __syncthreads();

    if (threadIdx.x >= 64) return;
    int n = blockIdx.x * 64 + (int)threadIdx.x;
    if (n >= NN) return;

    float ev[KK];
    float dh = 0.f;
#pragma unroll
    for (int j = 0; j < KK; ++j) {
        ev[j] = ebuf[threadIdx.x * KK + j];
        dh += ev[j];
    }

    const float* XC = xabc + 2 * (size_t)NN * HH + (size_t)n * HH;
    const float* w1l = dw1 + DD * HH;

    float acc[HH];
#pragma unroll
    for (int j = 0; j < HH; ++j) acc[j] = 0.f;

    float4 c4 = *(const float4*)XC;
#pragma unroll 1
    for (int i4 = 0; i4 < HH / 4; ++i4) {
        float4 c = c4;
        int nx = (i4 + 1 < 16) ? (i4 + 1) : 15;
        c4 = *(const float4*)(XC + nx * 4);
        float cv[4] = {c.x, c.y, c.z, c.w};
#pragma unroll
        for (int m = 0; m < 4; ++m) {
            int k = i4 * 4 + m;
            float g = fmaxf(cv[m] + dh * w1l[k] + db1[k], 0.f);
            const float* wr = dw2 + k * HH;
#pragma unroll
            for (int j4 = 0; j4 < 16; ++j4) {
                float4 w = *(const float4*)(wr + j4 * 4);
                acc[j4 * 4 + 0] = fmaf(g, w.x, acc[j4 * 4 + 0]);
                acc[j4 * 4 + 1] = fmaf(g, w.y, acc[j4 * 4 + 1]);
                acc[j4 * 4 + 2] = fmaf(g, w.z, acc[j4 * 4 + 2]);
                acc[j4 * 4 + 3] = fmaf(g, w.w, acc[j4 * 4 + 3]);
            }
        }
    }
    float kraw = db3[0];
#pragma unroll
    for (int j = 0; j < HH; ++j)
        kraw = fmaf(fmaxf(acc[j] + db2[j], 0.f), dw3[j], kraw);

    float kcont = 2.f + 13.f / (1.f + expf(-kraw));
    out[3 * (size_t)NKE + n] = kcont;

    // register-resident sort of (energy desc, idx asc), 16-wide network
    float se[16];
    int si[16];
#pragma unroll
    for (int j = 0; j < KK; ++j) { se[j] = ev[j]; si[j] = j; }
    se[15] = -1.f; si[15] = 15;

#pragma unroll
    for (int p = 1; p < 16; p <<= 1) {
#pragma unroll
        for (int k = p; k >= 1; k >>= 1) {
#pragma unroll
            for (int j = k & (p - 1); j + k < 16; j += 2 * k) {
#pragma unroll
                for (int i = 0; i < k; ++i) {
                    int a = i + j, b = i + j + k;
                    if (b < 16 && (a / (2 * p)) == (b / (2 * p))) {
                        bool sw = (se[b] > se[a]) ||
                                  (se[b] == se[a] && si[b] < si[a]);
                        float ea = sw ? se[b] : se[a];
                        float eb = sw ? se[a] : se[b];
                        int ia = sw ? si[b] : si[a];
                        int ib = sw ? si[a] : si[b];
                        se[a] = ea; se[b] = eb; si[a] = ia; si[b] = ib;
                    }
                }
            }
        }
    }

    float kint = rintf(kcont);
    kint = fminf(fmaxf(kint, 2.f), 15.f);

    float wsrt[KK];
    float denom = 0.f;
#pragma unroll
    for (int r = 0; r < KK; ++r) {
        float sel = ((float)(r + 1) <= kint) ? 1.f : 0.f;
        float wvv = se[r] * sel;
        wsrt[r] = wvv;
        denom += wvv;
    }
    denom = fmaxf(denom, 1e-12f);

#pragma unroll
    for (int r = 0; r < KK; ++r) {
        float sel = ((float)(r + 1) <= kint) ? 1.f : 0.f;
        int j0 = si[r];
        out[(size_t)NKE + (size_t)n * KK + j0] = sel;     // edge_gate
        out[(size_t)n * KK + j0] = wsrt[r] / denom;       // edge_weight
    }
}

// ---------------------------------------------------------------------------
// kP_fb: fallback if ws_size cannot hold xT (not expected — R7 proved the
// big path runs).  R6 kP, writes XA/XB/XC at xabc.
// ---------------------------------------------------------------------------
__global__ __launch_bounds__(256, 4) void kP_fb(const float* __restrict__ x,
                                                const float* __restrict__ ew1,
                                                const float* __restrict__ dw1,
                                                float* __restrict__ xabc) {
    int lane = threadIdx.x & 63;
    int wv = threadIdx.x >> 6;
    int r0 = blockIdx.x * 32 + wv * 8;
    if (r0 >= NN) return;
    const float* W0 = ew1;
    const float* W1 = ew1 + DD * HH;
    const float* W2 = dw1;
    const float* xw = x + (size_t)r0 * DD;
    float a0[8], a1[8], a2[8];
#pragma unroll
    for (int r = 0; r < 8; ++r) { a0[r] = 0.f; a1[r] = 0.f; a2[r] = 0.f; }
#pragma unroll 1
    for (int i4 = 0; i4 < DD / 4; ++i4) {
        float w00 = W0[(i4 * 4 + 0) * HH + lane];
        float w01 = W0[(i4 * 4 + 1) * HH + lane];
        float w02 = W0[(i4 * 4 + 2) * HH + lane];
        float w03 = W0[(i4 * 4 + 3) * HH + lane];
        float w10 = W1[(i4 * 4 + 0) * HH + lane];
        float w11 = W1[(i4 * 4 + 1) * HH + lane];
        float w12 = W1[(i4 * 4 + 2) * HH + lane];
        float w13 = W1[(i4 * 4 + 3) * HH + lane];
        float w20 = W2[(i4 * 4 + 0) * HH + lane];
        float w21 = W2[(i4 * 4 + 1) * HH + lane];
        float w22 = W2[(i4 * 4 + 2) * HH + lane];
        float w23 = W2[(i4 * 4 + 3) * HH + lane];
#pragma unroll
        for (int r = 0; r < 8; ++r) {
            float4 xv = *(const float4*)(xw + r * DD + i4 * 4);
            a0[r] = fmaf(xv.x, w00, a0[r]); a0[r] = fmaf(xv.y, w01, a0[r]);
            a0[r] = fmaf(xv.z, w02, a0[r]); a0[r] = fmaf(xv.w, w03, a0[r]);
            a1[r] = fmaf(xv.x, w10, a1[r]); a1[r] = fmaf(xv.y, w11, a1[r]);
            a1[r] = fmaf(xv.z, w12, a1[r]); a1[r] = fmaf(xv.w, w13, a1[r]);
            a2[r] = fmaf(xv.x, w20, a2[r]); a2[r] = fmaf(xv.y, w21, a2[r]);
            a2[r] = fmaf(xv.z, w22, a2[r]); a2[r] = fmaf(xv.w, w23, a2[r]);
        }
    }
    float* o0 = xabc + (size_t)r0 * HH + lane;
    float* o1 = xabc + (size_t)NN * HH + (size_t)r0 * HH + lane;
    float* o2 = xabc + 2 * (size_t)NN * HH + (size_t)r0 * HH + lane;
#pragma unroll
    for (int r = 0; r < 8; ++r) {
        o0[r * HH] = a0[r]; o1[r * HH] = a1[r]; o2[r * HH] = a2[r];
    }
}

extern "C" void kernel_launch(void* const* d_in, const int* in_sizes, int n_in,
                              void* d_out, int out_size, void* d_ws, size_t ws_size,
                              hipStream_t stream) {
    const float* x   = (const float*)d_in[0];
    const int*   ei  = (const int*)d_in[1];
    const float* ed  = (const float*)d_in[2];
    const float* ew1 = (const float*)d_in[3];
    const float* eb1 = (const float*)d_in[4];
    const float* ew2 = (const float*)d_in[5];
    const float* eb2 = (const float*)d_in[6];
    const float* ew3 = (const float*)d_in[7];
    const float* eb3 = (const float*)d_in[8];
    const float* dw1 = (const float*)d_in[9];
    const float* db1 = (const float*)d_in[10];
    const float* dw2 = (const float*)d_in[11];
    const float* db2 = (const float*)d_in[12];
    const float* dw3 = (const float*)d_in[13];
    const float* db3 = (const float*)d_in[14];
    float* out = (float*)d_out;
    float* ws  = (float*)d_ws;

    bool big = (ws_size >= WS_NEED);
    float* xabc = big ? (ws + TOFF) : ws;

    if (big) {
        hipLaunchKernelGGL(kT, dim3((NN + 63) / 64), dim3(256), 0, stream, x, ws);
        hipLaunchKernelGGL(kP4, dim3((NN + 127) / 128, 3), dim3(256), 0, stream,
                           ws, ew1, dw1, xabc);
    } else {
        hipLaunchKernelGGL(kP_fb, dim3((NN + 31) / 32), dim3(256), 0, stream,
                           x, ew1, dw1, xabc);
    }
    hipLaunchKernelGGL(kEF, dim3((NKE + 959) / 960), dim3(960), 0, stream,
                       ei, ed, xabc, ew1, eb1, ew2, eb2, ew3, eb3,
                       dw1, db1, dw2, db2, dw3, db3, out);
}

// Round 10
// 270.553 us; speedup vs baseline: 1.9633x; 1.9633x over previous
//
#include <hip/hip_runtime.h>
#include <cmath>

#define NN 50000
#define KK 15
#define DD 128
#define HH 64
#define NKE (NN * KK)
// ws layout (big path): [ xT : DD*NN ][ XA : NN*HH ][ XB : NN*HH ][ XC : NN*HH ]
#define TOFF ((size_t)DD * NN)
#define WS_NEED ((TOFF + 3 * (size_t)NN * HH) * 4)

// ---------------------------------------------------------------------------
// kT: transpose x (NN x DD) -> xT (DD x NN) via padded LDS tile.
// ---------------------------------------------------------------------------
__global__ __launch_bounds__(256) void kT(const float* __restrict__ x,
                                          float* __restrict__ xT) {
    __shared__ float s[64][DD + 1];
    int t = threadIdx.x;
    int r0 = blockIdx.x * 64;
#pragma unroll
    for (int i = 0; i < 8; ++i) {
        int idx = i * 256 + t;
        int rr = idx >> 5, cc = idx & 31;
        if (r0 + rr < NN) {
            float4 v = *(const float4*)(x + (size_t)(r0 + rr) * DD + cc * 4);
            s[rr][cc * 4 + 0] = v.x; s[rr][cc * 4 + 1] = v.y;
            s[rr][cc * 4 + 2] = v.z; s[rr][cc * 4 + 3] = v.w;
        }
    }
    __syncthreads();
    int lane = t & 63, wq = t >> 6;
    int n = r0 + lane;
    if (n >= NN) return;
#pragma unroll
    for (int i = 0; i < 32; ++i) {
        int k = i * 4 + wq;
        xT[(size_t)k * NN + n] = s[lane][k];
    }
}

// ---------------------------------------------------------------------------
// kP6: per-node GEMM, J-QUARTER split for occupancy (the fix for kP2's
// 2.3 waves/SIMD starvation; kP2's operand paths were healthy per counters).
// thread = (seg, jq, n): grid (196, 12), block 256 -> 600K threads = 9375
// waves (~9/SIMD).  acc[16]; xT dword loads coalesced (lane=n); W quarter
// rows (64 B) -> per-wave s_load stream 8 KB < sK$ (no kP4-style thrash),
// batched 4 k-rows per drain; stores 64 B/thread (sector-aligned).
// No LDS, no barrier, no cross-thread reduction (k ascending: same
// accumulation order as prior passing rounds).
// ---------------------------------------------------------------------------
__global__ __launch_bounds__(256, 8) void kP6(const float* __restrict__ xT,
                                              const float* __restrict__ ew1,
                                              const float* __restrict__ dw1,
                                              float* __restrict__ xabc) {
    int n = blockIdx.x * 256 + threadIdx.x;
    if (n >= NN) return;
    int seg = blockIdx.y >> 2;
    int jq  = blockIdx.y & 3;
    const float* W = ((seg == 0) ? ew1 : (seg == 1) ? (ew1 + DD * HH) : dw1)
                     + jq * 16;

    float acc[16];
#pragma unroll
    for (int j = 0; j < 16; ++j) acc[j] = 0.f;

#pragma unroll 1
    for (int k4 = 0; k4 < DD / 4; ++k4) {
        // 4 coalesced x loads (lane = n)
        float xk[4];
#pragma unroll
        for (int m = 0; m < 4; ++m)
            xk[m] = xT[(size_t)(k4 * 4 + m) * NN + n];
        // 4 uniform W quarter-rows batched (4 x 64 B), one drain
        float4 w[4][4];
#pragma unroll
        for (int m = 0; m < 4; ++m) {
            const float* wr = W + (k4 * 4 + m) * HH;
            w[m][0] = *(const float4*)(wr + 0);
            w[m][1] = *(const float4*)(wr + 4);
            w[m][2] = *(const float4*)(wr + 8);
            w[m][3] = *(const float4*)(wr + 12);
        }
#pragma unroll
        for (int m = 0; m < 4; ++m) {
#pragma unroll
            for (int q = 0; q < 4; ++q) {
                acc[q * 4 + 0] = fmaf(xk[m], w[m][q].x, acc[q * 4 + 0]);
                acc[q * 4 + 1] = fmaf(xk[m], w[m][q].y, acc[q * 4 + 1]);
                acc[q * 4 + 2] = fmaf(xk[m], w[m][q].z, acc[q * 4 + 2]);
                acc[q * 4 + 3] = fmaf(xk[m], w[m][q].w, acc[q * 4 + 3]);
            }
        }
    }
    float* o = xabc + (size_t)seg * NN * HH + (size_t)n * HH + jq * 16;
#pragma unroll
    for (int q = 0; q < 4; ++q) {
        float4 v;
        v.x = acc[q * 4 + 0]; v.y = acc[q * 4 + 1];
        v.z = acc[q * 4 + 2]; v.w = acc[q * 4 + 3];
        *(float4*)(o + q * 4) = v;                 // 64 B contiguous/thread
    }
}

// ---------------------------------------------------------------------------
// kEF2: fused edge-MLP + node-MLP + sort, block 256 = 240 edges (16 nodes).
// launch_bounds (256,4) = kE's proven register budget (NOT R9's (960,4)
// spill bomb).  Phase 1: kE verbatim for threads 0..239, energy -> global
// + 960 B LDS.  Barrier.  Phase 2: threads 0..15 run the node MLP (acc[64],
// s_load dw2) + register sort + gate + normalize.  Phase-2 : phase-1 work
// = 1:60, hidden under other resident blocks.  3125 blocks = 12.5K waves.
// ---------------------------------------------------------------------------
__global__ __launch_bounds__(256, 4) void kEF2(const int* __restrict__ srcIdx,
                                               const float* __restrict__ dist,
                                               const float* __restrict__ xabc,
                                               const float* __restrict__ ew1,
                                               const float* __restrict__ eb1,
                                               const float* __restrict__ ew2,
                                               const float* __restrict__ eb2,
                                               const float* __restrict__ ew3,
                                               const float* __restrict__ eb3,
                                               const float* __restrict__ dw1,
                                               const float* __restrict__ db1,
                                               const float* __restrict__ dw2,
                                               const float* __restrict__ db2,
                                               const float* __restrict__ dw3,
                                               const float* __restrict__ db3,
                                               float* __restrict__ out) {
    __shared__ float ebuf[240];
    int tid = threadIdx.x;
    float* energy_out = out + 2 * (size_t)NKE;

    if (tid < 240) {
        int e = blockIdx.x * 240 + tid;            // always < NKE (exact tiling)
        int s = srcIdx[e];
        int d = e / KK;
        float dd = dist[e];
        const float* A = xabc + (size_t)d * HH;
        const float* B = xabc + (size_t)NN * HH + (size_t)s * HH;
        const float* w1l = ew1 + 2 * DD * HH;

        float acc[HH];
#pragma unroll
        for (int j = 0; j < HH; ++j) acc[j] = 0.f;

        float4 a4 = *(const float4*)A;
        float4 bp0 = *(const float4*)B;
        float4 bp1 = *(const float4*)(B + 4);
#pragma unroll 1
        for (int i4 = 0; i4 < HH / 4; ++i4) {
            float4 a = a4, b = bp0;
            int n1 = (i4 + 1 < 16) ? (i4 + 1) : 15;
            int n2 = (i4 + 2 < 16) ? (i4 + 2) : 15;
            a4 = *(const float4*)(A + n1 * 4);
            bp0 = bp1;
            bp1 = *(const float4*)(B + n2 * 4);
            float h[4];
            h[0] = fmaxf(a.x + b.x + dd * w1l[i4 * 4 + 0] + eb1[i4 * 4 + 0], 0.f);
            h[1] = fmaxf(a.y + b.y + dd * w1l[i4 * 4 + 1] + eb1[i4 * 4 + 1], 0.f);
            h[2] = fmaxf(a.z + b.z + dd * w1l[i4 * 4 + 2] + eb1[i4 * 4 + 2], 0.f);
            h[3] = fmaxf(a.w + b.w + dd * w1l[i4 * 4 + 3] + eb1[i4 * 4 + 3], 0.f);
#pragma unroll
            for (int k = 0; k < 4; ++k) {
                const float* wr = ew2 + (i4 * 4 + k) * HH;
#pragma unroll
                for (int j4 = 0; j4 < 16; ++j4) {
                    float4 w = *(const float4*)(wr + j4 * 4);
                    acc[j4 * 4 + 0] = fmaf(h[k], w.x, acc[j4 * 4 + 0]);
                    acc[j4 * 4 + 1] = fmaf(h[k], w.y, acc[j4 * 4 + 1]);
                    acc[j4 * 4 + 2] = fmaf(h[k], w.z, acc[j4 * 4 + 2]);
                    acc[j4 * 4 + 3] = fmaf(h[k], w.w, acc[j4 * 4 + 3]);
                }
            }
        }
        float lg = eb3[0];
#pragma unroll
        for (int j = 0; j < HH; ++j)
            lg = fmaf(fmaxf(acc[j] + eb2[j], 0.f), ew3[j], lg);
        float en = 1.f / (1.f + expf(-2.f * lg));
        energy_out[e] = en;
        ebuf[tid] = en;
    }
    __syncthreads();

    if (tid >= 16) return;
    int n = blockIdx.x * 16 + tid;                 // always < NN (exact tiling)

    float ev[KK];
    float dh = 0.f;
#pragma unroll
    for (int j = 0; j < KK; ++j) {
        ev[j] = ebuf[tid * KK + j];
        dh += ev[j];
    }

    const float* XC = xabc + 2 * (size_t)NN * HH + (size_t)n * HH;
    const float* w1l = dw1 + DD * HH;

    float acc[HH];
#pragma unroll
    for (int j = 0; j < HH; ++j) acc[j] = 0.f;

    float4 c4 = *(const float4*)XC;
#pragma unroll 1
    for (int i4 = 0; i4 < HH / 4; ++i4) {
        float4 c = c4;
        int nx = (i4 + 1 < 16) ? (i4 + 1) : 15;
        c4 = *(const float4*)(XC + nx * 4);
        float cv[4] = {c.x, c.y, c.z, c.w};
#pragma unroll
        for (int m = 0; m < 4; ++m) {
            int k = i4 * 4 + m;
            float g = fmaxf(cv[m] + dh * w1l[k] + db1[k], 0.f);
            const float* wr = dw2 + k * HH;
#pragma unroll
            for (int j4 = 0; j4 < 16; ++j4) {
                float4 w = *(const float4*)(wr + j4 * 4);
                acc[j4 * 4 + 0] = fmaf(g, w.x, acc[j4 * 4 + 0]);
                acc[j4 * 4 + 1] = fmaf(g, w.y, acc[j4 * 4 + 1]);
                acc[j4 * 4 + 2] = fmaf(g, w.z, acc[j4 * 4 + 2]);
                acc[j4 * 4 + 3] = fmaf(g, w.w, acc[j4 * 4 + 3]);
            }
        }
    }
    float kraw = db3[0];
#pragma unroll
    for (int j = 0; j < HH; ++j)
        kraw = fmaf(fmaxf(acc[j] + db2[j], 0.f), dw3[j], kraw);

    float kcont = 2.f + 13.f / (1.f + expf(-kraw));
    out[3 * (size_t)NKE + n] = kcont;

    // register-resident sort of (energy desc, idx asc), 16-wide network
    float se[16];
    int si[16];
#pragma unroll
    for (int j = 0; j < KK; ++j) { se[j] = ev[j]; si[j] = j; }
    se[15] = -1.f; si[15] = 15;

#pragma unroll
    for (int p = 1; p < 16; p <<= 1) {
#pragma unroll
        for (int k = p; k >= 1; k >>= 1) {
#pragma unroll
            for (int j = k & (p - 1); j + k < 16; j += 2 * k) {
#pragma unroll
                for (int i = 0; i < k; ++i) {
                    int a = i + j, b = i + j + k;
                    if (b < 16 && (a / (2 * p)) == (b / (2 * p))) {
                        bool sw = (se[b] > se[a]) ||
                                  (se[b] == se[a] && si[b] < si[a]);
                        float ea = sw ? se[b] : se[a];
                        float eb = sw ? se[a] : se[b];
                        int ia = sw ? si[b] : si[a];
                        int ib = sw ? si[a] : si[b];
                        se[a] = ea; se[b] = eb; si[a] = ia; si[b] = ib;
                    }
                }
            }
        }
    }

    float kint = rintf(kcont);
    kint = fminf(fmaxf(kint, 2.f), 15.f);

    float wsrt[KK];
    float denom = 0.f;
#pragma unroll
    for (int r = 0; r < KK; ++r) {
        float sel = ((float)(r + 1) <= kint) ? 1.f : 0.f;
        float wvv = se[r] * sel;
        wsrt[r] = wvv;
        denom += wvv;
    }
    denom = fmaxf(denom, 1e-12f);

#pragma unroll
    for (int r = 0; r < KK; ++r) {
        float sel = ((float)(r + 1) <= kint) ? 1.f : 0.f;
        int j0 = si[r];
        out[(size_t)NKE + (size_t)n * KK + j0] = sel;     // edge_gate
        out[(size_t)n * KK + j0] = wsrt[r] / denom;       // edge_weight
    }
}

// ---------------------------------------------------------------------------
// kP_fb: fallback if ws cannot hold xT (not expected).
// ---------------------------------------------------------------------------
__global__ __launch_bounds__(256, 4) void kP_fb(const float* __restrict__ x,
                                                const float* __restrict__ ew1,
                                                const float* __restrict__ dw1,
                                                float* __restrict__ xabc) {
    int lane = threadIdx.x & 63;
    int wv = threadIdx.x >> 6;
    int r0 = blockIdx.x * 32 + wv * 8;
    if (r0 >= NN) return;
    const float* W0 = ew1;
    const float* W1 = ew1 + DD * HH;
    const float* W2 = dw1;
    const float* xw = x + (size_t)r0 * DD;
    float a0[8], a1[8], a2[8];
#pragma unroll
    for (int r = 0; r < 8; ++r) { a0[r] = 0.f; a1[r] = 0.f; a2[r] = 0.f; }
#pragma unroll 1
    for (int i4 = 0; i4 < DD / 4; ++i4) {
        float w00 = W0[(i4 * 4 + 0) * HH + lane];
        float w01 = W0[(i4 * 4 + 1) * HH + lane];
        float w02 = W0[(i4 * 4 + 2) * HH + lane];
        float w03 = W0[(i4 * 4 + 3) * HH + lane];
        float w10 = W1[(i4 * 4 + 0) * HH + lane];
        float w11 = W1[(i4 * 4 + 1) * HH + lane];
        float w12 = W1[(i4 * 4 + 2) * HH + lane];
        float w13 = W1[(i4 * 4 + 3) * HH + lane];
        float w20 = W2[(i4 * 4 + 0) * HH + lane];
        float w21 = W2[(i4 * 4 + 1) * HH + lane];
        float w22 = W2[(i4 * 4 + 2) * HH + lane];
        float w23 = W2[(i4 * 4 + 3) * HH + lane];
#pragma unroll
        for (int r = 0; r < 8; ++r) {
            float4 xv = *(const float4*)(xw + r * DD + i4 * 4);
            a0[r] = fmaf(xv.x, w00, a0[r]); a0[r] = fmaf(xv.y, w01, a0[r]);
            a0[r] = fmaf(xv.z, w02, a0[r]); a0[r] = fmaf(xv.w, w03, a0[r]);
            a1[r] = fmaf(xv.x, w10, a1[r]); a1[r] = fmaf(xv.y, w11, a1[r]);
            a1[r] = fmaf(xv.z, w12, a1[r]); a1[r] = fmaf(xv.w, w13, a1[r]);
            a2[r] = fmaf(xv.x, w20, a2[r]); a2[r] = fmaf(xv.y, w21, a2[r]);
            a2[r] = fmaf(xv.z, w22, a2[r]); a2[r] = fmaf(xv.w, w23, a2[r]);
        }
    }
    float* o0 = xabc + (size_t)r0 * HH + lane;
    float* o1 = xabc + (size_t)NN * HH + (size_t)r0 * HH + lane;
    float* o2 = xabc + 2 * (size_t)NN * HH + (size_t)r0 * HH + lane;
#pragma unroll
    for (int r = 0; r < 8; ++r) {
        o0[r * HH] = a0[r]; o1[r * HH] = a1[r]; o2[r * HH] = a2[r];
    }
}

extern "C" void kernel_launch(void* const* d_in, const int* in_sizes, int n_in,
                              void* d_out, int out_size, void* d_ws, size_t ws_size,
                              hipStream_t stream) {
    const float* x   = (const float*)d_in[0];
    const int*   ei  = (const int*)d_in[1];
    const float* ed  = (const float*)d_in[2];
    const float* ew1 = (const float*)d_in[3];
    const float* eb1 = (const float*)d_in[4];
    const float* ew2 = (const float*)d_in[5];
    const float* eb2 = (const float*)d_in[6];
    const float* ew3 = (const float*)d_in[7];
    const float* eb3 = (const float*)d_in[8];
    const float* dw1 = (const float*)d_in[9];
    const float* db1 = (const float*)d_in[10];
    const float* dw2 = (const float*)d_in[11];
    const float* db2 = (const float*)d_in[12];
    const float* dw3 = (const float*)d_in[13];
    const float* db3 = (const float*)d_in[14];
    float* out = (float*)d_out;
    float* ws  = (float*)d_ws;

    bool big = (ws_size >= WS_NEED);
    float* xabc = big ? (ws + TOFF) : ws;

    if (big) {
        hipLaunchKernelGGL(kT, dim3((NN + 63) / 64), dim3(256), 0, stream, x, ws);
        hipLaunchKernelGGL(kP6, dim3((NN + 255) / 256, 12), dim3(256), 0, stream,
                           ws, ew1, dw1, xabc);
    } else {
        hipLaunchKernelGGL(kP_fb, dim3((NN + 31) / 32), dim3(256), 0, stream,
                           x, ew1, dw1, xabc);
    }
    hipLaunchKernelGGL(kEF2, dim3(NKE / 240), dim3(256), 0, stream,
                       ei, ed, xabc, ew1, eb1, ew2, eb2, ew3, eb3,
                       dw1, db1, dw2, db2, dw3, db3, out);
}